// Round 12
// baseline (818.185 us; speedup 1.0000x reference)
//
#include <hip/hip_runtime.h>
#include <stdint.h>

#define B_ 4
#define N_TOK 1024
#define DM 256
#define DEPTH 12
#define DSTATE 16
#define DIN 512
#define LVIS 768
#define MROWS (B_ * LVIS)  // 3072
#define NCHUNK 64
#define CLEN 12            // 768 / 64
#define EPS_F 1e-5f
#define YS 520             // bf16 LDS row stride (shorts); 1040B, 16B-aligned
#define AS_ 264            // rms A-tile stride (shorts)
#define LOG2E 1.4426950408889634f
#define LN2   0.6931471805599453f

typedef __attribute__((ext_vector_type(8))) short s8v;   // 8 bf16 (4 VGPRs)
typedef __attribute__((ext_vector_type(4))) float f4v;   // 4 f32 acc

// ---------- helpers ----------
__device__ __forceinline__ float bs2f(uint32_t u) {
  uint32_t x = (u & 0xffffu) << 16;
  float f; __builtin_memcpy(&f, &x, 4); return f;
}
__device__ __forceinline__ uint16_t f2b(float f) {
  uint32_t u; __builtin_memcpy(&u, &f, 4);
  return (uint16_t)((u + 0x7fffu + ((u >> 16) & 1u)) >> 16);
}
// hardware-native transcendentals (round-7 win: single-op v_exp/v_log/v_rcp,
// ~1ulp, fine vs 0.0156 absmax tolerance)
__device__ __forceinline__ float exp2_f(float x) {
  float r; asm("v_exp_f32 %0, %1" : "=v"(r) : "v"(x)); return r;
}
__device__ __forceinline__ float log2_f(float x) {
  float r; asm("v_log_f32 %0, %1" : "=v"(r) : "v"(x)); return r;
}
__device__ __forceinline__ float rcp_f(float x) {
  float r; asm("v_rcp_f32 %0, %1" : "=v"(r) : "v"(x)); return r;
}
__device__ __forceinline__ float silu_f(float x) {
  return x * rcp_f(1.f + exp2_f(-x * LOG2E));
}
__device__ __forceinline__ float softplus_f(float x) {
  float t = exp2_f(-fabsf(x) * LOG2E);
  return fmaxf(x, 0.f) + log2_f(1.f + t) * LN2;
}
__device__ __forceinline__ float block_sum256(float v, volatile float* scr) {
  int t = threadIdx.x, lane = t & 63, wid = t >> 6;
#pragma unroll
  for (int o = 32; o > 0; o >>= 1) v += __shfl_down(v, o);
  __syncthreads();
  if (lane == 0) scr[wid] = v;
  __syncthreads();
  return scr[0] + scr[1] + scr[2] + scr[3];
}

// ---------- dtype detection ----------
__global__ void detect_kernel(const void* mask, const uint32_t* nf, int* flags) {
  __shared__ int cnt[3];
  int t = threadIdx.x;
  if (t < 3) cnt[t] = 0;
  __syncthreads();
  const uint32_t* pi = (const uint32_t*)mask;
  const uint16_t* ph = (const uint16_t*)mask;
  const uint8_t*  pb = (const uint8_t*)mask;
  int c32 = 0, cbf = 0, c8 = 0;
  for (int i = t; i < 1024; i += 256) {
    c32 += (pi[i] != 0u);
    cbf += (ph[i] != 0);
    c8  += (pb[i] != 0);
  }
  atomicAdd(&cnt[0], c32);
  atomicAdd(&cnt[1], cbf);
  atomicAdd(&cnt[2], c8);
  __syncthreads();
  if (t == 0) {
    int f;
    if (cnt[0] == 256) f = 0;
    else if (cnt[1] == 256) f = 2;
    else f = 1;
    flags[0] = f;
    flags[1] = (nf[0] == 0x3F800000u) ? 0 : 1;
  }
}

// ---------- single batched conversion of all 13 param arrays ----------
struct CvtArgs {
  const void* src[13];
  void*       dst[13];
  int         n[13];
  int         isb16[13];
};
__global__ __launch_bounds__(256) void cvt_all_kernel(CvtArgs a, int total,
                                                      const int* __restrict__ flags) {
  int e = blockIdx.x * 256 + threadIdx.x;
  if (e >= total) return;
  int i = 0;
  while (e >= a.n[i]) { e -= a.n[i]; ++i; }
  int srcb16 = flags[1];
  if (a.isb16[i]) {
    uint16_t v = srcb16 ? ((const uint16_t*)a.src[i])[e]
                        : f2b(((const float*)a.src[i])[e]);
    ((uint16_t*)a.dst[i])[e] = v;
  } else {
    float v = srcb16 ? bs2f(((const uint16_t*)a.src[i])[e])
                     : ((const float*)a.src[i])[e];
    ((float*)a.dst[i])[e] = v;
  }
}

// ---------- visible-index compaction (stable) ----------
__global__ __launch_bounds__(1024) void order_kernel(const void* mask,
                                                     const int* __restrict__ flags,
                                                     int* __restrict__ order) {
  int b = blockIdx.x, i = threadIdx.x;
  int f = flags[0];
  int mv;
  if (f == 0)      mv = (((const uint32_t*)mask)[b * N_TOK + i] != 0u);
  else if (f == 1) mv = (((const uint8_t*)mask)[b * N_TOK + i] != 0);
  else             mv = (((const uint16_t*)mask)[b * N_TOK + i] != 0);
  int vis = !mv;
  unsigned long long mb = __ballot(vis);
  int lane = i & 63, wid = i >> 6;
  int wpre = __popcll(mb & ((1ull << lane) - 1ull));
  __shared__ int wsum[16];
  __shared__ int woff[16];
  if (lane == 0) wsum[wid] = __popcll(mb);
  __syncthreads();
  if (i == 0) { int a = 0; for (int w = 0; w < 16; ++w) { woff[w] = a; a += wsum[w]; } }
  __syncthreads();
  if (vis) {
    int pos = woff[wid] + wpre;
    if (pos < LVIS) order[b * LVIS + pos] = i;
  }
}

// ---------- gather tokens -> residual (= r_1); rms -> rmsb16 ----------
__global__ __launch_bounds__(256) void gather_rms_kernel(const void* __restrict__ tokens,
                                                         const int* __restrict__ order,
                                                         const int* __restrict__ flags,
                                                         const float* __restrict__ nw,
                                                         float* __restrict__ residual,
                                                         uint16_t* __restrict__ rmsb16) {
  __shared__ float scr[4];
  int row = blockIdx.x;
  int b = row / LVIS;
  int d = threadIdx.x;
  int idx = order[row];
  size_t src = ((size_t)(b * N_TOK + idx)) * DM + d;
  float v = flags[1] ? bs2f(((const uint16_t*)tokens)[src]) : ((const float*)tokens)[src];
  size_t i = (size_t)row * DM + d;
  residual[i] = v;
  float ss = block_sum256(v * v, scr);
  rmsb16[i] = f2b(v * rsqrtf(ss / DM + EPS_F) * nw[d]);
}

// carry-state layout: idx(b,c,s,d) = ((b*NCHUNK + c)*16 + s)*DIN + d  (d innermost)
__device__ __forceinline__ size_t cidx(int b, int c, int s, int d) {
  return (((size_t)(b * NCHUNK + c) * 16 + s)) * DIN + d;
}

// ---------- scan1: in_proj GEMM + conv+silu + x_proj + chunk-local scan ----
// R11 structure (786us best). Round-12 edit: z copy-out now runs on waves
// 8-15 CONCURRENTLY with waves 0-7's conv+x_proj (was: all-wave copy-out in
// its own barrier slot). zt gets its own LDS (no aliasing with red); red
// shrunk to its 12 live rows so static LDS stays at 62.4KB < 64KB. One
// barrier removed; copy-out stores drain under the conv phase.
__global__ __launch_bounds__(1024, 4) void scan1_kernel(
    const uint16_t* __restrict__ rmsb16, const uint16_t* __restrict__ inw,
    const uint16_t* __restrict__ xw,
    const float* __restrict__ cw, const float* __restrict__ cb,
    const float* __restrict__ dtw, const float* __restrict__ dtb,
    const float* __restrict__ Alog, const float* __restrict__ Dsk,
    uint16_t* __restrict__ zh16, float* __restrict__ hend,
    float* __restrict__ xdbl_out, float* __restrict__ yloc,
    float* __restrict__ Ssum) {
  __shared__ uint16_t As[16 * AS_];   // rms input tile (16 x 256), 8448 B
  __shared__ uint16_t xzl[16 * YS];   // x-half of in_proj output, 16640 B
  __shared__ uint16_t zt[16 * YS];    // z-half bounce tile, 16640 B
  __shared__ float red[8][CLEN * 48]; // x_proj split-K partials (12 rows), 18432 B
  __shared__ float xds[CLEN * 48];    // 2304 B                    (total 62464 B)
  const int t = threadIdx.x;
  const int wv = t >> 6, lane = t & 63;
  const int lm = lane & 15, lq = lane >> 4;
  const int c = blockIdx.x & (NCHUNK - 1);
  const int b = blockIdx.x >> 6;
  const int rowbase = b * LVIS + c * CLEN;
  // ---- stage rms A-tile: tile row i <-> global row clamp(rowbase-3+i) ----
  if (t < 512) {
    int r = t >> 5, seg = t & 31;
    int grow = rowbase - 3 + r;
    if (grow < 0) grow = 0;
    if (grow > MROWS - 1) grow = MROWS - 1;
    *(uint4*)(As + r * AS_ + seg * 8) =
        *(const uint4*)(rmsb16 + (size_t)grow * DM + seg * 8);
  }
  __syncthreads();
  // ---- in_proj GEMM: wave wv -> n-tiles 4wv..4wv+3 (cols 64wv..64wv+63) ----
  {
    f4v acc[4];
#pragma unroll
    for (int j = 0; j < 4; ++j) acc[j] = (f4v){0.f, 0.f, 0.f, 0.f};
    for (int k0 = 0; k0 < DM; k0 += 32) {
      s8v a = *(const s8v*)(As + lm * AS_ + k0 + lq * 8);
#pragma unroll
      for (int j = 0; j < 4; ++j) {
        int n = (4 * wv + j) * 16 + lm;
        s8v bw = *(const s8v*)(inw + (size_t)n * DM + k0 + lq * 8);
        acc[j] = __builtin_amdgcn_mfma_f32_16x16x32_bf16(a, bw, acc[j], 0, 0, 0);
      }
    }
#pragma unroll
    for (int j = 0; j < 4; ++j) {
      int col = (4 * wv + j) * 16 + lm;
#pragma unroll
      for (int rr = 0; rr < 4; ++rr) {
        int tr = lq * 4 + rr;            // tile row 0..15
        uint16_t v = f2b(acc[j][rr]);
        if (col < 512) xzl[tr * YS + col] = v;        // x half
        else           zt[tr * YS + (col - 512)] = v; // z half
      }
    }
  }
  __syncthreads();
  // ---- waves 0-7: conv+silu + x_proj GEMM (split-K-8, K-slice 64 / wave)
  //      waves 8-15: coalesced z copy-out (overlapped; round-12) ----
  if (wv < 8) {
    f4v acc[3];
#pragma unroll
    for (int j = 0; j < 3; ++j) acc[j] = (f4v){0.f, 0.f, 0.f, 0.f};
    const int l = c * CLEN + lm;         // position within batch row
    const bool t3 = l >= 3, t2 = l >= 2, t1 = l >= 1;
#pragma unroll
    for (int ki = 0; ki < 2; ++ki) {
      int kk = wv * 64 + ki * 32 + lq * 8;
      s8v a8 = {0, 0, 0, 0, 0, 0, 0, 0};
      if (lm < CLEN) {
        const s8v zv = {0, 0, 0, 0, 0, 0, 0, 0};
        s8v x0 = *(const s8v*)(xzl + (lm + 3) * YS + kk);
        s8v x1 = t1 ? *(const s8v*)(xzl + (lm + 2) * YS + kk) : zv;
        s8v x2 = t2 ? *(const s8v*)(xzl + (lm + 1) * YS + kk) : zv;
        s8v x3 = t3 ? *(const s8v*)(xzl + (lm + 0) * YS + kk) : zv;
#pragma unroll
        for (int j = 0; j < 8; ++j) {
          int ch = kk + j;
          float4 w = *(const float4*)(cw + ch * 4);
          float a = cb[ch] + bs2f((uint16_t)x3[j]) * w.x +
                    bs2f((uint16_t)x2[j]) * w.y +
                    bs2f((uint16_t)x1[j]) * w.z + bs2f((uint16_t)x0[j]) * w.w;
          a8[j] = (short)f2b(silu_f(a));
        }
      }
#pragma unroll
      for (int j = 0; j < 3; ++j) {
        s8v bb = *(const s8v*)(xw + (size_t)(j * 16 + lm) * DIN + kk);
        acc[j] = __builtin_amdgcn_mfma_f32_16x16x32_bf16(a8, bb, acc[j], 0, 0, 0);
      }
    }
#pragma unroll
    for (int j = 0; j < 3; ++j)
#pragma unroll
      for (int rr = 0; rr < 4; ++rr) {
        int row = lq * 4 + rr;
        if (row < CLEN)
          red[wv][row * 48 + j * 16 + lm] = acc[j][rr];
      }
  } else {
    for (int e = t - 512; e < 768; e += 512) {
      int r = e >> 6, q = e & 63;
      *(uint4*)(zh16 + (size_t)(rowbase + r) * 512 + q * 8) =
          *(const uint4*)(zt + (3 + r) * YS + q * 8);
    }
  }
  __syncthreads();
  if (t < CLEN * 48) {
    float v = red[0][t] + red[1][t] + red[2][t] + red[3][t] +
              red[4][t] + red[5][t] + red[6][t] + red[7][t];
    xds[t] = v;
    int k = t % 48;
    if (k >= 32)   // export C-slice only (scan3 reads nothing else)
      xdbl_out[(size_t)(rowbase + t / 48) * 16 + (k - 32)] = v;
  }
  __syncthreads();
  // ---- scan phase: lane-pair split, all 1024 threads ----
  {
    const int d = t >> 1;
    const int s0 = (t & 1) * 8;
    float A2[8], dw[16];
    {
      const float4* ap = (const float4*)(Alog + (size_t)d * 16 + s0);
      const float4* wp = (const float4*)(dtw + (size_t)d * 16);
#pragma unroll
      for (int q = 0; q < 2; ++q) {
        float4 a4 = ap[q];
        A2[4 * q + 0] = -__expf(a4.x) * LOG2E;
        A2[4 * q + 1] = -__expf(a4.y) * LOG2E;
        A2[4 * q + 2] = -__expf(a4.z) * LOG2E;
        A2[4 * q + 3] = -__expf(a4.w) * LOG2E;
      }
#pragma unroll
      for (int q = 0; q < 4; ++q) {
        float4 w4 = wp[q];
        dw[4 * q + 0] = w4.x; dw[4 * q + 1] = w4.y;
        dw[4 * q + 2] = w4.z; dw[4 * q + 3] = w4.w;
      }
    }
    float dtbv = dtb[d], cbv = cb[d], Dv = Dsk[d];
    float4 cwv = *(const float4*)(cw + d * 4);
    float w3 = 0.f, w2 = 0.f, w1 = 0.f;
    if (c > 0) {
      w3 = bs2f(xzl[0 * YS + d]);
      w2 = bs2f(xzl[1 * YS + d]);
      w1 = bs2f(xzl[2 * YS + d]);
    }
    float h[8];
#pragma unroll
    for (int i = 0; i < 8; ++i) h[i] = 0.f;
    float S = 0.f;
    for (int l = 0; l < CLEN; ++l) {
      float xn = bs2f(xzl[(l + 3) * YS + d]);
      float xv = silu_f(cbv + w3 * cwv.x + w2 * cwv.y + w1 * cwv.z + xn * cwv.w);
      w3 = w2; w2 = w1; w1 = xn;
      const float* xd = xds + l * 48;
      float dtraw = dtbv;
#pragma unroll
      for (int q = 0; q < 16; ++q) dtraw += xd[q] * dw[q];
      float dtv = softplus_f(dtraw);
      float dtx = dtv * xv;
      S += dtv;
      float y = 0.f;
#pragma unroll
      for (int i = 0; i < 8; ++i) {
        float dA = exp2_f(dtv * A2[i]);
        h[i] = dA * h[i] + dtx * xd[16 + s0 + i];
        y += h[i] * xd[32 + s0 + i];
      }
      y += __shfl_xor(y, 1);            // combine the two 8-state halves
      if (!(t & 1)) {
        size_t oi = (size_t)(rowbase + l) * DIN + d;
        yloc[oi] = y + Dv * xv;
        Ssum[oi] = S;
      }
    }
#pragma unroll
    for (int i = 0; i < 8; ++i)
      hend[cidx(b, c, s0 + i, d)] = h[i];
  }
}

// ---------- scan2: segmented cross-chunk carry scan (serial depth 16+3) ----
// pend recomputed from Ssum (P_i = exp2(A2.Send_i)) — bit-identical (R11).
__global__ __launch_bounds__(256) void scan2_kernel(const float* __restrict__ hend,
                                                    const float* __restrict__ Ssum,
                                                    const float* __restrict__ Alog,
                                                    float* __restrict__ hin) {
  __shared__ float sP[4 * 64];
  __shared__ float sE[4 * 64];
  int t = threadIdx.x;
  int w = t >> 6, lane = t & 63;    // w = segment (16 chunks each)
  int chain = blockIdx.x * 64 + lane;
  int d = chain & (DIN - 1);
  int s = (chain >> 9) & 15;
  int b = chain >> 13;
  float A2v = -__expf(Alog[(size_t)d * 16 + s]) * LOG2E;
  float P = 1.f, E = 0.f;
  float pr[16], hr[16];
#pragma unroll
  for (int i = 0; i < 16; ++i) {
    int cc = w * 16 + i;
    float Send = Ssum[(size_t)(b * LVIS + cc * CLEN + CLEN - 1) * DIN + d];
    float pv = exp2_f(A2v * Send);
    float ev = hend[cidx(b, cc, s, d)];
    pr[i] = pv; hr[i] = ev;
    E = pv * E + ev;
    P *= pv;
  }
  sP[w * 64 + lane] = P;
  sE[w * 64 + lane] = E;
  __syncthreads();
  float hc = 0.f;
#pragma unroll
  for (int j = 0; j < 3; ++j)
    if (j < w) hc = sP[j * 64 + lane] * hc + sE[j * 64 + lane];
#pragma unroll
  for (int i = 0; i < 16; ++i) {
    hin[cidx(b, w * 16 + i, s, d)] = hc;
    hc = pr[i] * hc + hr[i];
  }
}

// ---------- scan3: carry-apply + gate + out_proj + residual + rms ----------
// Round-12: carry loop lane-pair split (d=t>>1, 8 states each, shfl combine)
// — halves the exp2 chain and activates all 16 waves (was 8).
template <int LAST>
__global__ __launch_bounds__(1024, 4) void scan3_fused_kernel(
    const uint16_t* __restrict__ zh16, const float* __restrict__ xdbl,
    const float* __restrict__ Alog, const float* __restrict__ hin,
    const float* __restrict__ yloc, const float* __restrict__ Ssum,
    const uint16_t* __restrict__ W, const float* __restrict__ nw,
    float* __restrict__ residual, uint16_t* __restrict__ rmsb16,
    const float* __restrict__ nfw, const float* __restrict__ lnw,
    const float* __restrict__ lnb, const int* __restrict__ flags,
    void* __restrict__ out) {
  __shared__ float xds[CLEN * 16];
  __shared__ uint16_t yml[16 * YS];
  __shared__ float part[16][16];
  __shared__ float scale[16];
  const int t = threadIdx.x;
  const int c = blockIdx.x & (NCHUNK - 1);
  const int b = blockIdx.x >> 6;
  const int rowbase = b * LVIS + c * CLEN;
  if (t < CLEN * 16)
    xds[t] = xdbl[(size_t)(rowbase + t / 16) * 16 + (t % 16)];
  for (int e = t; e < 4 * 512; e += 1024)
    yml[(12 + (e >> 9)) * YS + (e & 511)] = 0;
  __syncthreads();
  // ---- carry-apply + gate: lane-pair split, all 1024 threads ----
  {
    const int d = t >> 1;
    const int s0 = (t & 1) * 8;
    float A2[8];
    {
      const float4* ap = (const float4*)(Alog + (size_t)d * 16 + s0);
#pragma unroll
      for (int q = 0; q < 2; ++q) {
        float4 a4 = ap[q];
        A2[4 * q + 0] = -__expf(a4.x) * LOG2E;
        A2[4 * q + 1] = -__expf(a4.y) * LOG2E;
        A2[4 * q + 2] = -__expf(a4.z) * LOG2E;
        A2[4 * q + 3] = -__expf(a4.w) * LOG2E;
      }
    }
    float chin[8];
#pragma unroll
    for (int i = 0; i < 8; ++i) chin[i] = hin[cidx(b, c, s0 + i, d)];
    for (int l = 0; l < CLEN; ++l) {
      int row = rowbase + l;
      size_t oi = (size_t)row * DIN + d;
      float S = Ssum[oi];
      float yl = yloc[oi];
      const float* xd = xds + l * 16;
      float carry = 0.f;
#pragma unroll
      for (int i = 0; i < 8; ++i)
        carry += xd[s0 + i] * chin[i] * exp2_f(A2[i] * S);
      carry += __shfl_xor(carry, 1);    // combine the two 8-state halves
      if (!(t & 1)) {
        float zv = bs2f(zh16[(size_t)row * 512 + d]);
        yml[l * YS + d] = f2b((yl + carry) * silu_f(zv));
      }
    }
  }
  __syncthreads();
  // ---- out_proj GEMM: wave wv -> col tile wv (cols 16wv..16wv+15) ----
  {
    const int wv = t >> 6, lane = t & 63;
    const int lm = lane & 15, lq = lane >> 4;
    const int col = wv * 16 + lm;
    f4v acc = (f4v){0.f, 0.f, 0.f, 0.f};
    for (int k0 = 0; k0 < DIN; k0 += 32) {
      s8v a = *(const s8v*)(yml + lm * YS + k0 + lq * 8);
      s8v bf = *(const s8v*)(W + (size_t)col * DIN + k0 + lq * 8);
      acc = __builtin_amdgcn_mfma_f32_16x16x32_bf16(a, bf, acc, 0, 0, 0);
    }
    float vv[4];
    float sum[4] = {0.f, 0.f, 0.f, 0.f};
#pragma unroll
    for (int rr = 0; rr < 4; ++rr) {
      int row = lq * 4 + rr;
      if (row < CLEN) {
        float v = acc[rr] + residual[(size_t)(rowbase + row) * DM + col];
        vv[rr] = v;
        sum[rr] += v * v;
      }
    }
#pragma unroll
    for (int rr = 0; rr < 4; ++rr) {
#pragma unroll
      for (int o = 1; o < 16; o <<= 1) sum[rr] += __shfl_xor(sum[rr], o);
    }
    if (lm == 0) {
#pragma unroll
      for (int rr = 0; rr < 4; ++rr) {
        int row = lq * 4 + rr;
        if (row < 16) part[row][wv] = sum[rr];
      }
    }
    __syncthreads();
    if (t < CLEN) {
      float s = 0.f;
#pragma unroll
      for (int w = 0; w < 16; ++w) s += part[t][w];
      scale[t] = rsqrtf(s / DM + EPS_F);
    }
    __syncthreads();
    if (!LAST) {
#pragma unroll
      for (int rr = 0; rr < 4; ++rr) {
        int row = lq * 4 + rr;
        if (row < CLEN) {
          float sc = scale[row];
          float v = vv[rr];
          size_t oi = (size_t)(rowbase + row) * DM + col;
          residual[oi] = v;
          rmsb16[oi] = f2b(v * sc * nw[col]);
        }
      }
    } else {
      // ---- fused final: rmsnorm(norm_f) -> layernorm -> typed out ----
      float hv[4];
      float mu[4] = {0.f, 0.f, 0.f, 0.f};
#pragma unroll
      for (int rr = 0; rr < 4; ++rr) {
        int row = lq * 4 + rr;
        hv[rr] = 0.f;
        if (row < CLEN) {
          hv[rr] = vv[rr] * scale[row] * nfw[col];
          mu[rr] = hv[rr];
        }
      }
#pragma unroll
      for (int rr = 0; rr < 4; ++rr) {
#pragma unroll
        for (int o = 1; o < 16; o <<= 1) mu[rr] += __shfl_xor(mu[rr], o);
      }
      __syncthreads();   // everyone done reading scale (round 1)
      if (lm == 0) {
#pragma unroll
        for (int rr = 0; rr < 4; ++rr) {
          int row = lq * 4 + rr;
          if (row < 16) part[row][wv] = mu[rr];
        }
      }
      __syncthreads();
      if (t < CLEN) {
        float s = 0.f;
#pragma unroll
        for (int w = 0; w < 16; ++w) s += part[t][w];
        scale[t] = s / DM;               // mean
      }
      __syncthreads();
      float dv_[4];
      float va[4] = {0.f, 0.f, 0.f, 0.f};
#pragma unroll
      for (int rr = 0; rr < 4; ++rr) {
        int row = lq * 4 + rr;
        dv_[rr] = 0.f;
        if (row < CLEN) {
          dv_[rr] = hv[rr] - scale[row];
          va[rr] = dv_[rr] * dv_[rr];
        }
      }
#pragma unroll
      for (int rr = 0; rr < 4; ++rr) {
#pragma unroll
        for (int o = 1; o < 16; o <<= 1) va[rr] += __shfl_xor(va[rr], o);
      }
      __syncthreads();   // everyone done reading scale (round 2)
      if (lm == 0) {
#pragma unroll
        for (int rr = 0; rr < 4; ++rr) {
          int row = lq * 4 + rr;
          if (row < 16) part[row][wv] = va[rr];
        }
      }
      __syncthreads();
      if (t < CLEN) {
        float s = 0.f;
#pragma unroll
        for (int w = 0; w < 16; ++w) s += part[t][w];
        scale[t] = rsqrtf(s / DM + EPS_F);
      }
      __syncthreads();
      int f1 = flags[1];
#pragma unroll
      for (int rr = 0; rr < 4; ++rr) {
        int row = lq * 4 + rr;
        if (row < CLEN) {
          float o = dv_[rr] * scale[row] * lnw[col] + lnb[col];
          int l2 = c * CLEN + row;
          size_t oi = (l2 < LVIS - 1)
                        ? ((size_t)(b * (LVIS - 1) + l2) * DM + col)
                        : ((size_t)B_ * (LVIS - 1) * DM + (size_t)b * DM + col);
          if (f1) ((uint16_t*)out)[oi] = f2b(o);
          else    ((float*)out)[oi] = o;
        }
      }
    }
  }
}

// ---------- host ----------
extern "C" void kernel_launch(void* const* d_in, const int* in_sizes, int n_in,
                              void* d_out, int out_size, void* d_ws, size_t ws_size,
                              hipStream_t stream) {
  char* ws = (char*)d_ws;
  size_t off = 0;
  auto alloc = [&](size_t bytes) -> void* {
    void* p = ws + off;
    off += (bytes + 255) & ~(size_t)255;
    return p;
  };
  const int f32_idx[10] = {3, 4, 6, 7, 8, 9, 11, 12, 13, 14};
  const int b16_idx[3]  = {2, 5, 10};
  float*    f32c[15] = {nullptr};
  uint16_t* b16c[15] = {nullptr};
  for (int j = 0; j < 10; ++j) {
    int i = f32_idx[j];
    f32c[i] = (float*)alloc((size_t)in_sizes[i] * 4);
  }
  for (int j = 0; j < 3; ++j) {
    int i = b16_idx[j];
    b16c[i] = (uint16_t*)alloc((size_t)in_sizes[i] * 2);
  }
  float*    residual = (float*)alloc((size_t)MROWS * DM * 4);
  uint16_t* rmsb16   = (uint16_t*)alloc((size_t)MROWS * DM * 2);
  uint16_t* zh16     = (uint16_t*)alloc((size_t)MROWS * 512 * 2);
  float*    xdbl     = (float*)alloc((size_t)MROWS * 16 * 4);
  float*    hend     = (float*)alloc((size_t)B_ * NCHUNK * DIN * 16 * 4);
  float*    hin      = (float*)alloc((size_t)B_ * NCHUNK * DIN * 16 * 4);
  float*    yloc     = (float*)alloc((size_t)MROWS * DIN * 4);
  float*    Ssum     = (float*)alloc((size_t)MROWS * DIN * 4);
  int*      order    = (int*)alloc((size_t)B_ * LVIS * 4);
  int*      flags    = (int*)alloc(256);

  detect_kernel<<<1, 256, 0, stream>>>(d_in[1], (const uint32_t*)d_in[12], flags);

  CvtArgs ca;
  int total = 0, slot = 0;
  for (int j = 0; j < 3; ++j) {
    int i = b16_idx[j];
    ca.src[slot] = d_in[i]; ca.dst[slot] = b16c[i];
    ca.n[slot] = in_sizes[i]; ca.isb16[slot] = 1;
    total += in_sizes[i]; ++slot;
  }
  for (int j = 0; j < 10; ++j) {
    int i = f32_idx[j];
    ca.src[slot] = d_in[i]; ca.dst[slot] = f32c[i];
    ca.n[slot] = in_sizes[i]; ca.isb16[slot] = 0;
    total += in_sizes[i]; ++slot;
  }
  cvt_all_kernel<<<(total + 255) / 256, 256, 0, stream>>>(ca, total, flags);

  const uint16_t* in_w   = b16c[2];
  const float*    conv_w = f32c[3];
  const float*    conv_b = f32c[4];
  const uint16_t* x_w    = b16c[5];
  const float*    dt_w   = f32c[6];
  const float*    dt_b   = f32c[7];
  const float*    A_log  = f32c[8];
  const float*    D_skip = f32c[9];
  const uint16_t* out_w  = b16c[10];
  const float*    norm_w = f32c[11];
  const float*    norm_f = f32c[12];
  const float*    ln_w   = f32c[13];
  const float*    ln_b   = f32c[14];

  order_kernel<<<B_, 1024, 0, stream>>>(d_in[1], flags, order);
  gather_rms_kernel<<<MROWS, 256, 0, stream>>>(d_in[0], order, flags, norm_w,
                                               residual, rmsb16);

  for (int L = 0; L < DEPTH; ++L) {
    scan1_kernel<<<B_ * NCHUNK, 1024, 0, stream>>>(
        rmsb16, in_w + (size_t)L * 1024 * DM, x_w + (size_t)L * 48 * DIN,
        conv_w + (size_t)L * DIN * 4, conv_b + (size_t)L * DIN,
        dt_w + (size_t)L * DIN * 16, dt_b + (size_t)L * DIN,
        A_log + (size_t)L * DIN * 16, D_skip + (size_t)L * DIN,
        zh16, hend, xdbl, yloc, Ssum);
    scan2_kernel<<<(B_ * 16 * DIN * 4) / 256, 256, 0, stream>>>(
        hend, Ssum, A_log + (size_t)L * DIN * 16, hin);
    int Lnext = (L + 1 < DEPTH) ? (L + 1) : L;
    if (L + 1 < DEPTH) {
      scan3_fused_kernel<0><<<B_ * NCHUNK, 1024, 0, stream>>>(
          zh16, xdbl, A_log + (size_t)L * DIN * 16, hin, yloc, Ssum,
          out_w + (size_t)L * DM * DIN, norm_w + (size_t)Lnext * DM,
          residual, rmsb16, norm_f, ln_w, ln_b, flags, d_out);
    } else {
      scan3_fused_kernel<1><<<B_ * NCHUNK, 1024, 0, stream>>>(
          zh16, xdbl, A_log + (size_t)L * DIN * 16, hin, yloc, Ssum,
          out_w + (size_t)L * DM * DIN, norm_w + (size_t)Lnext * DM,
          residual, rmsb16, norm_f, ln_w, ln_b, flags, d_out);
    }
  }
}

// Round 13
// 781.242 us; speedup vs baseline: 1.0473x; 1.0473x over previous
//
#include <hip/hip_runtime.h>
#include <stdint.h>

#define B_ 4
#define N_TOK 1024
#define DM 256
#define DEPTH 12
#define DSTATE 16
#define DIN 512
#define LVIS 768
#define MROWS (B_ * LVIS)  // 3072
#define NCHUNK 64
#define CLEN 12            // 768 / 64
#define EPS_F 1e-5f
#define YS 520             // bf16 LDS row stride (shorts); 1040B, 16B-aligned
#define AS_ 264            // rms A-tile stride (shorts)
#define LOG2E 1.4426950408889634f
#define LN2   0.6931471805599453f

typedef __attribute__((ext_vector_type(8))) short s8v;   // 8 bf16 (4 VGPRs)
typedef __attribute__((ext_vector_type(4))) float f4v;   // 4 f32 acc

// ---------- helpers ----------
__device__ __forceinline__ float bs2f(uint32_t u) {
  uint32_t x = (u & 0xffffu) << 16;
  float f; __builtin_memcpy(&f, &x, 4); return f;
}
__device__ __forceinline__ uint16_t f2b(float f) {
  uint32_t u; __builtin_memcpy(&u, &f, 4);
  return (uint16_t)((u + 0x7fffu + ((u >> 16) & 1u)) >> 16);
}
// hardware-native transcendentals (round-7 win: single-op v_exp/v_log/v_rcp,
// ~1ulp, fine vs 0.0156 absmax tolerance)
__device__ __forceinline__ float exp2_f(float x) {
  float r; asm("v_exp_f32 %0, %1" : "=v"(r) : "v"(x)); return r;
}
__device__ __forceinline__ float log2_f(float x) {
  float r; asm("v_log_f32 %0, %1" : "=v"(r) : "v"(x)); return r;
}
__device__ __forceinline__ float rcp_f(float x) {
  float r; asm("v_rcp_f32 %0, %1" : "=v"(r) : "v"(x)); return r;
}
__device__ __forceinline__ float silu_f(float x) {
  return x * rcp_f(1.f + exp2_f(-x * LOG2E));
}
__device__ __forceinline__ float softplus_f(float x) {
  float t = exp2_f(-fabsf(x) * LOG2E);
  return fmaxf(x, 0.f) + log2_f(1.f + t) * LN2;
}
__device__ __forceinline__ float block_sum256(float v, volatile float* scr) {
  int t = threadIdx.x, lane = t & 63, wid = t >> 6;
#pragma unroll
  for (int o = 32; o > 0; o >>= 1) v += __shfl_down(v, o);
  __syncthreads();
  if (lane == 0) scr[wid] = v;
  __syncthreads();
  return scr[0] + scr[1] + scr[2] + scr[3];
}

// ---------- dtype detection ----------
__global__ void detect_kernel(const void* mask, const uint32_t* nf, int* flags) {
  __shared__ int cnt[3];
  int t = threadIdx.x;
  if (t < 3) cnt[t] = 0;
  __syncthreads();
  const uint32_t* pi = (const uint32_t*)mask;
  const uint16_t* ph = (const uint16_t*)mask;
  const uint8_t*  pb = (const uint8_t*)mask;
  int c32 = 0, cbf = 0, c8 = 0;
  for (int i = t; i < 1024; i += 256) {
    c32 += (pi[i] != 0u);
    cbf += (ph[i] != 0);
    c8  += (pb[i] != 0);
  }
  atomicAdd(&cnt[0], c32);
  atomicAdd(&cnt[1], cbf);
  atomicAdd(&cnt[2], c8);
  __syncthreads();
  if (t == 0) {
    int f;
    if (cnt[0] == 256) f = 0;
    else if (cnt[1] == 256) f = 2;
    else f = 1;
    flags[0] = f;
    flags[1] = (nf[0] == 0x3F800000u) ? 0 : 1;
  }
}

// ---------- single batched conversion of all 13 param arrays ----------
struct CvtArgs {
  const void* src[13];
  void*       dst[13];
  int         n[13];
  int         isb16[13];
};
__global__ __launch_bounds__(256) void cvt_all_kernel(CvtArgs a, int total,
                                                      const int* __restrict__ flags) {
  int e = blockIdx.x * 256 + threadIdx.x;
  if (e >= total) return;
  int i = 0;
  while (e >= a.n[i]) { e -= a.n[i]; ++i; }
  int srcb16 = flags[1];
  if (a.isb16[i]) {
    uint16_t v = srcb16 ? ((const uint16_t*)a.src[i])[e]
                        : f2b(((const float*)a.src[i])[e]);
    ((uint16_t*)a.dst[i])[e] = v;
  } else {
    float v = srcb16 ? bs2f(((const uint16_t*)a.src[i])[e])
                     : ((const float*)a.src[i])[e];
    ((float*)a.dst[i])[e] = v;
  }
}

// ---------- visible-index compaction (stable) ----------
__global__ __launch_bounds__(1024) void order_kernel(const void* mask,
                                                     const int* __restrict__ flags,
                                                     int* __restrict__ order) {
  int b = blockIdx.x, i = threadIdx.x;
  int f = flags[0];
  int mv;
  if (f == 0)      mv = (((const uint32_t*)mask)[b * N_TOK + i] != 0u);
  else if (f == 1) mv = (((const uint8_t*)mask)[b * N_TOK + i] != 0);
  else             mv = (((const uint16_t*)mask)[b * N_TOK + i] != 0);
  int vis = !mv;
  unsigned long long mb = __ballot(vis);
  int lane = i & 63, wid = i >> 6;
  int wpre = __popcll(mb & ((1ull << lane) - 1ull));
  __shared__ int wsum[16];
  __shared__ int woff[16];
  if (lane == 0) wsum[wid] = __popcll(mb);
  __syncthreads();
  if (i == 0) { int a = 0; for (int w = 0; w < 16; ++w) { woff[w] = a; a += wsum[w]; } }
  __syncthreads();
  if (vis) {
    int pos = woff[wid] + wpre;
    if (pos < LVIS) order[b * LVIS + pos] = i;
  }
}

// ---------- gather tokens -> residual (= r_1); rms -> rmsb16 ----------
__global__ __launch_bounds__(256) void gather_rms_kernel(const void* __restrict__ tokens,
                                                         const int* __restrict__ order,
                                                         const int* __restrict__ flags,
                                                         const float* __restrict__ nw,
                                                         float* __restrict__ residual,
                                                         uint16_t* __restrict__ rmsb16) {
  __shared__ float scr[4];
  int row = blockIdx.x;
  int b = row / LVIS;
  int d = threadIdx.x;
  int idx = order[row];
  size_t src = ((size_t)(b * N_TOK + idx)) * DM + d;
  float v = flags[1] ? bs2f(((const uint16_t*)tokens)[src]) : ((const float*)tokens)[src];
  size_t i = (size_t)row * DM + d;
  residual[i] = v;
  float ss = block_sum256(v * v, scr);
  rmsb16[i] = f2b(v * rsqrtf(ss / DM + EPS_F) * nw[d]);
}

// carry-state layout: idx(b,c,s,d) = ((b*NCHUNK + c)*16 + s)*DIN + d  (d innermost)
__device__ __forceinline__ size_t cidx(int b, int c, int s, int d) {
  return (((size_t)(b * NCHUNK + c) * 16 + s)) * DIN + d;
}

// ---------- scan1: in_proj GEMM + conv+silu + x_proj + chunk-local scan ----
// R10 structure (788us best). Round-11 edits (best verified config, 786.7us):
//  - pend ELIMINATED (scan2 recomputes exp2(A2.Send) from Ssum — bit-identical,
//    saves 16.8 MB/layer of round-trip traffic + 16 exp2/thread here).
//  - xdbl export shrunk to the C-slice only (scan3 reads nothing else).
//  - scan phase lane-pair split: d=t>>1, 8 states/lane, all 16 waves active.
// Round-12's overlapped-copy-out and scan3 carry-split both REGRESSED — reverted.
__global__ __launch_bounds__(1024, 4) void scan1_kernel(
    const uint16_t* __restrict__ rmsb16, const uint16_t* __restrict__ inw,
    const uint16_t* __restrict__ xw,
    const float* __restrict__ cw, const float* __restrict__ cb,
    const float* __restrict__ dtw, const float* __restrict__ dtb,
    const float* __restrict__ Alog, const float* __restrict__ Dsk,
    uint16_t* __restrict__ zh16, float* __restrict__ hend,
    float* __restrict__ xdbl_out, float* __restrict__ yloc,
    float* __restrict__ Ssum) {
  __shared__ uint16_t As[16 * AS_];   // rms input tile (16 x 256)
  __shared__ uint16_t xzl[16 * YS];   // x-half of in_proj output (16 x 512)
  __shared__ float red[8][768];       // conv/x_proj partials; aliased as zt
  __shared__ float xds[CLEN * 48];
  uint16_t* zt = (uint16_t*)red;      // z-half bounce tile (16 x YS shorts)
  const int t = threadIdx.x;
  const int wv = t >> 6, lane = t & 63;
  const int lm = lane & 15, lq = lane >> 4;
  const int c = blockIdx.x & (NCHUNK - 1);
  const int b = blockIdx.x >> 6;
  const int rowbase = b * LVIS + c * CLEN;
  // ---- stage rms A-tile: tile row i <-> global row clamp(rowbase-3+i) ----
  if (t < 512) {
    int r = t >> 5, seg = t & 31;
    int grow = rowbase - 3 + r;
    if (grow < 0) grow = 0;
    if (grow > MROWS - 1) grow = MROWS - 1;
    *(uint4*)(As + r * AS_ + seg * 8) =
        *(const uint4*)(rmsb16 + (size_t)grow * DM + seg * 8);
  }
  __syncthreads();
  // ---- in_proj GEMM: wave wv -> n-tiles 4wv..4wv+3 (cols 64wv..64wv+63) ----
  {
    f4v acc[4];
#pragma unroll
    for (int j = 0; j < 4; ++j) acc[j] = (f4v){0.f, 0.f, 0.f, 0.f};
    for (int k0 = 0; k0 < DM; k0 += 32) {
      s8v a = *(const s8v*)(As + lm * AS_ + k0 + lq * 8);
#pragma unroll
      for (int j = 0; j < 4; ++j) {
        int n = (4 * wv + j) * 16 + lm;
        s8v bw = *(const s8v*)(inw + (size_t)n * DM + k0 + lq * 8);
        acc[j] = __builtin_amdgcn_mfma_f32_16x16x32_bf16(a, bw, acc[j], 0, 0, 0);
      }
    }
#pragma unroll
    for (int j = 0; j < 4; ++j) {
      int col = (4 * wv + j) * 16 + lm;
#pragma unroll
      for (int rr = 0; rr < 4; ++rr) {
        int tr = lq * 4 + rr;            // tile row 0..15
        uint16_t v = f2b(acc[j][rr]);
        if (col < 512) xzl[tr * YS + col] = v;        // x half -> LDS
        else           zt[tr * YS + (col - 512)] = v; // z half -> LDS bounce
      }
    }
  }
  __syncthreads();
  // ---- coalesced z copy-out: owned rows 3..14 -> zh16[rowbase..rowbase+11] ----
  if (t < 768) {
    int r = t >> 6, q = t & 63;
    *(uint4*)(zh16 + (size_t)(rowbase + r) * 512 + q * 8) =
        *(const uint4*)(zt + (3 + r) * YS + q * 8);
  }
  __syncthreads();                      // zt dead after this; red reusable
  // ---- conv+silu + x_proj GEMM (split-K-8, K-slice 64 / wave; waves 0-7) ----
  if (wv < 8) {
    f4v acc[3];
#pragma unroll
    for (int j = 0; j < 3; ++j) acc[j] = (f4v){0.f, 0.f, 0.f, 0.f};
    const int l = c * CLEN + lm;         // position within batch row
    const bool t3 = l >= 3, t2 = l >= 2, t1 = l >= 1;
#pragma unroll
    for (int ki = 0; ki < 2; ++ki) {
      int kk = wv * 64 + ki * 32 + lq * 8;
      s8v a8 = {0, 0, 0, 0, 0, 0, 0, 0};
      if (lm < CLEN) {
        const s8v zv = {0, 0, 0, 0, 0, 0, 0, 0};
        s8v x0 = *(const s8v*)(xzl + (lm + 3) * YS + kk);
        s8v x1 = t1 ? *(const s8v*)(xzl + (lm + 2) * YS + kk) : zv;
        s8v x2 = t2 ? *(const s8v*)(xzl + (lm + 1) * YS + kk) : zv;
        s8v x3 = t3 ? *(const s8v*)(xzl + (lm + 0) * YS + kk) : zv;
#pragma unroll
        for (int j = 0; j < 8; ++j) {
          int ch = kk + j;
          float4 w = *(const float4*)(cw + ch * 4);
          float a = cb[ch] + bs2f((uint16_t)x3[j]) * w.x +
                    bs2f((uint16_t)x2[j]) * w.y +
                    bs2f((uint16_t)x1[j]) * w.z + bs2f((uint16_t)x0[j]) * w.w;
          a8[j] = (short)f2b(silu_f(a));
        }
      }
#pragma unroll
      for (int j = 0; j < 3; ++j) {
        s8v bb = *(const s8v*)(xw + (size_t)(j * 16 + lm) * DIN + kk);
        acc[j] = __builtin_amdgcn_mfma_f32_16x16x32_bf16(a8, bb, acc[j], 0, 0, 0);
      }
    }
#pragma unroll
    for (int j = 0; j < 3; ++j)
#pragma unroll
      for (int rr = 0; rr < 4; ++rr)
        red[wv][(lq * 4 + rr) * 48 + j * 16 + lm] = acc[j][rr];
  }
  __syncthreads();
  if (t < CLEN * 48) {
    float v = red[0][t] + red[1][t] + red[2][t] + red[3][t] +
              red[4][t] + red[5][t] + red[6][t] + red[7][t];
    xds[t] = v;
    int k = t % 48;
    if (k >= 32)   // export C-slice only (scan3 reads nothing else)
      xdbl_out[(size_t)(rowbase + t / 48) * 16 + (k - 32)] = v;
  }
  __syncthreads();
  // ---- scan phase: lane-pair split, all 1024 threads ----
  {
    const int d = t >> 1;
    const int s0 = (t & 1) * 8;
    float A2[8], dw[16];
    {
      const float4* ap = (const float4*)(Alog + (size_t)d * 16 + s0);
      const float4* wp = (const float4*)(dtw + (size_t)d * 16);
#pragma unroll
      for (int q = 0; q < 2; ++q) {
        float4 a4 = ap[q];
        A2[4 * q + 0] = -__expf(a4.x) * LOG2E;
        A2[4 * q + 1] = -__expf(a4.y) * LOG2E;
        A2[4 * q + 2] = -__expf(a4.z) * LOG2E;
        A2[4 * q + 3] = -__expf(a4.w) * LOG2E;
      }
#pragma unroll
      for (int q = 0; q < 4; ++q) {
        float4 w4 = wp[q];
        dw[4 * q + 0] = w4.x; dw[4 * q + 1] = w4.y;
        dw[4 * q + 2] = w4.z; dw[4 * q + 3] = w4.w;
      }
    }
    float dtbv = dtb[d], cbv = cb[d], Dv = Dsk[d];
    float4 cwv = *(const float4*)(cw + d * 4);
    float w3 = 0.f, w2 = 0.f, w1 = 0.f;
    if (c > 0) {
      w3 = bs2f(xzl[0 * YS + d]);
      w2 = bs2f(xzl[1 * YS + d]);
      w1 = bs2f(xzl[2 * YS + d]);
    }
    float h[8];
#pragma unroll
    for (int i = 0; i < 8; ++i) h[i] = 0.f;
    float S = 0.f;
    for (int l = 0; l < CLEN; ++l) {
      float xn = bs2f(xzl[(l + 3) * YS + d]);
      float xv = silu_f(cbv + w3 * cwv.x + w2 * cwv.y + w1 * cwv.z + xn * cwv.w);
      w3 = w2; w2 = w1; w1 = xn;
      const float* xd = xds + l * 48;
      float dtraw = dtbv;
#pragma unroll
      for (int q = 0; q < 16; ++q) dtraw += xd[q] * dw[q];
      float dtv = softplus_f(dtraw);
      float dtx = dtv * xv;
      S += dtv;
      float y = 0.f;
#pragma unroll
      for (int i = 0; i < 8; ++i) {
        float dA = exp2_f(dtv * A2[i]);
        h[i] = dA * h[i] + dtx * xd[16 + s0 + i];
        y += h[i] * xd[32 + s0 + i];
      }
      y += __shfl_xor(y, 1);            // combine the two 8-state halves
      if (!(t & 1)) {
        size_t oi = (size_t)(rowbase + l) * DIN + d;
        yloc[oi] = y + Dv * xv;
        Ssum[oi] = S;
      }
    }
#pragma unroll
    for (int i = 0; i < 8; ++i)
      hend[cidx(b, c, s0 + i, d)] = h[i];
  }
}

// ---------- scan2: segmented cross-chunk carry scan (serial depth 16+3) ----
// pend recomputed from Ssum (P_i = exp2(A2.Send_i)) — bit-identical (R11).
__global__ __launch_bounds__(256) void scan2_kernel(const float* __restrict__ hend,
                                                    const float* __restrict__ Ssum,
                                                    const float* __restrict__ Alog,
                                                    float* __restrict__ hin) {
  __shared__ float sP[4 * 64];
  __shared__ float sE[4 * 64];
  int t = threadIdx.x;
  int w = t >> 6, lane = t & 63;    // w = segment (16 chunks each)
  int chain = blockIdx.x * 64 + lane;
  int d = chain & (DIN - 1);
  int s = (chain >> 9) & 15;
  int b = chain >> 13;
  float A2v = -__expf(Alog[(size_t)d * 16 + s]) * LOG2E;
  float P = 1.f, E = 0.f;
  float pr[16], hr[16];
#pragma unroll
  for (int i = 0; i < 16; ++i) {
    int cc = w * 16 + i;
    float Send = Ssum[(size_t)(b * LVIS + cc * CLEN + CLEN - 1) * DIN + d];
    float pv = exp2_f(A2v * Send);
    float ev = hend[cidx(b, cc, s, d)];
    pr[i] = pv; hr[i] = ev;
    E = pv * E + ev;
    P *= pv;
  }
  sP[w * 64 + lane] = P;
  sE[w * 64 + lane] = E;
  __syncthreads();
  float hc = 0.f;
#pragma unroll
  for (int j = 0; j < 3; ++j)
    if (j < w) hc = sP[j * 64 + lane] * hc + sE[j * 64 + lane];
#pragma unroll
  for (int i = 0; i < 16; ++i) {
    hin[cidx(b, w * 16 + i, s, d)] = hc;
    hc = pr[i] * hc + hr[i];
  }
}

// ---------- scan3: carry-apply + gate + out_proj + residual + rms ----------
// No serial scan (round-7). LAST=1 fuses the final rmsnorm+layernorm+typed out.
template <int LAST>
__global__ __launch_bounds__(1024, 4) void scan3_fused_kernel(
    const uint16_t* __restrict__ zh16, const float* __restrict__ xdbl,
    const float* __restrict__ Alog, const float* __restrict__ hin,
    const float* __restrict__ yloc, const float* __restrict__ Ssum,
    const uint16_t* __restrict__ W, const float* __restrict__ nw,
    float* __restrict__ residual, uint16_t* __restrict__ rmsb16,
    const float* __restrict__ nfw, const float* __restrict__ lnw,
    const float* __restrict__ lnb, const int* __restrict__ flags,
    void* __restrict__ out) {
  __shared__ float xds[CLEN * 16];
  __shared__ uint16_t yml[16 * YS];
  __shared__ float part[16][16];
  __shared__ float scale[16];
  const int t = threadIdx.x;
  const int c = blockIdx.x & (NCHUNK - 1);
  const int b = blockIdx.x >> 6;
  const int rowbase = b * LVIS + c * CLEN;
  if (t < CLEN * 16)
    xds[t] = xdbl[(size_t)(rowbase + t / 16) * 16 + (t % 16)];
  for (int e = t; e < 4 * 512; e += 1024)
    yml[(12 + (e >> 9)) * YS + (e & 511)] = 0;
  __syncthreads();
  if (t < DIN) {
    const int d = t;
    float A2[16];
    {
      const float4* ap = (const float4*)(Alog + (size_t)d * 16);
#pragma unroll
      for (int q = 0; q < 4; ++q) {
        float4 a4 = ap[q];
        A2[4 * q + 0] = -__expf(a4.x) * LOG2E;
        A2[4 * q + 1] = -__expf(a4.y) * LOG2E;
        A2[4 * q + 2] = -__expf(a4.z) * LOG2E;
        A2[4 * q + 3] = -__expf(a4.w) * LOG2E;
      }
    }
    float chin[16];
#pragma unroll
    for (int s = 0; s < 16; ++s) chin[s] = hin[cidx(b, c, s, d)];
    for (int l = 0; l < CLEN; ++l) {
      int row = rowbase + l;
      size_t oi = (size_t)row * DIN + d;
      float S = Ssum[oi];
      float yl = yloc[oi];
      const float* xd = xds + l * 16;
      float carry = 0.f;
#pragma unroll
      for (int s = 0; s < 16; ++s)
        carry += xd[s] * chin[s] * exp2_f(A2[s] * S);
      float zv = bs2f(zh16[(size_t)row * 512 + d]);
      yml[l * YS + d] = f2b((yl + carry) * silu_f(zv));
    }
  }
  __syncthreads();
  // ---- out_proj GEMM: wave wv -> col tile wv (cols 16wv..16wv+15) ----
  {
    const int wv = t >> 6, lane = t & 63;
    const int lm = lane & 15, lq = lane >> 4;
    const int col = wv * 16 + lm;
    f4v acc = (f4v){0.f, 0.f, 0.f, 0.f};
    for (int k0 = 0; k0 < DIN; k0 += 32) {
      s8v a = *(const s8v*)(yml + lm * YS + k0 + lq * 8);
      s8v bf = *(const s8v*)(W + (size_t)col * DIN + k0 + lq * 8);
      acc = __builtin_amdgcn_mfma_f32_16x16x32_bf16(a, bf, acc, 0, 0, 0);
    }
    float vv[4];
    float sum[4] = {0.f, 0.f, 0.f, 0.f};
#pragma unroll
    for (int rr = 0; rr < 4; ++rr) {
      int row = lq * 4 + rr;
      if (row < CLEN) {
        float v = acc[rr] + residual[(size_t)(rowbase + row) * DM + col];
        vv[rr] = v;
        sum[rr] += v * v;
      }
    }
#pragma unroll
    for (int rr = 0; rr < 4; ++rr) {
#pragma unroll
      for (int o = 1; o < 16; o <<= 1) sum[rr] += __shfl_xor(sum[rr], o);
    }
    if (lm == 0) {
#pragma unroll
      for (int rr = 0; rr < 4; ++rr) {
        int row = lq * 4 + rr;
        if (row < 16) part[row][wv] = sum[rr];
      }
    }
    __syncthreads();
    if (t < CLEN) {
      float s = 0.f;
#pragma unroll
      for (int w = 0; w < 16; ++w) s += part[t][w];
      scale[t] = rsqrtf(s / DM + EPS_F);
    }
    __syncthreads();
    if (!LAST) {
#pragma unroll
      for (int rr = 0; rr < 4; ++rr) {
        int row = lq * 4 + rr;
        if (row < CLEN) {
          float sc = scale[row];
          float v = vv[rr];
          size_t oi = (size_t)(rowbase + row) * DM + col;
          residual[oi] = v;
          rmsb16[oi] = f2b(v * sc * nw[col]);
        }
      }
    } else {
      // ---- fused final: rmsnorm(norm_f) -> layernorm -> typed out ----
      float hv[4];
      float mu[4] = {0.f, 0.f, 0.f, 0.f};
#pragma unroll
      for (int rr = 0; rr < 4; ++rr) {
        int row = lq * 4 + rr;
        hv[rr] = 0.f;
        if (row < CLEN) {
          hv[rr] = vv[rr] * scale[row] * nfw[col];
          mu[rr] = hv[rr];
        }
      }
#pragma unroll
      for (int rr = 0; rr < 4; ++rr) {
#pragma unroll
        for (int o = 1; o < 16; o <<= 1) mu[rr] += __shfl_xor(mu[rr], o);
      }
      __syncthreads();   // everyone done reading scale (round 1)
      if (lm == 0) {
#pragma unroll
        for (int rr = 0; rr < 4; ++rr) {
          int row = lq * 4 + rr;
          if (row < 16) part[row][wv] = mu[rr];
        }
      }
      __syncthreads();
      if (t < CLEN) {
        float s = 0.f;
#pragma unroll
        for (int w = 0; w < 16; ++w) s += part[t][w];
        scale[t] = s / DM;               // mean
      }
      __syncthreads();
      float dv_[4];
      float va[4] = {0.f, 0.f, 0.f, 0.f};
#pragma unroll
      for (int rr = 0; rr < 4; ++rr) {
        int row = lq * 4 + rr;
        dv_[rr] = 0.f;
        if (row < CLEN) {
          dv_[rr] = hv[rr] - scale[row];
          va[rr] = dv_[rr] * dv_[rr];
        }
      }
#pragma unroll
      for (int rr = 0; rr < 4; ++rr) {
#pragma unroll
        for (int o = 1; o < 16; o <<= 1) va[rr] += __shfl_xor(va[rr], o);
      }
      __syncthreads();   // everyone done reading scale (round 2)
      if (lm == 0) {
#pragma unroll
        for (int rr = 0; rr < 4; ++rr) {
          int row = lq * 4 + rr;
          if (row < 16) part[row][wv] = va[rr];
        }
      }
      __syncthreads();
      if (t < CLEN) {
        float s = 0.f;
#pragma unroll
        for (int w = 0; w < 16; ++w) s += part[t][w];
        scale[t] = rsqrtf(s / DM + EPS_F);
      }
      __syncthreads();
      int f1 = flags[1];
#pragma unroll
      for (int rr = 0; rr < 4; ++rr) {
        int row = lq * 4 + rr;
        if (row < CLEN) {
          float o = dv_[rr] * scale[row] * lnw[col] + lnb[col];
          int l2 = c * CLEN + row;
          size_t oi = (l2 < LVIS - 1)
                        ? ((size_t)(b * (LVIS - 1) + l2) * DM + col)
                        : ((size_t)B_ * (LVIS - 1) * DM + (size_t)b * DM + col);
          if (f1) ((uint16_t*)out)[oi] = f2b(o);
          else    ((float*)out)[oi] = o;
        }
      }
    }
  }
}

// ---------- host ----------
extern "C" void kernel_launch(void* const* d_in, const int* in_sizes, int n_in,
                              void* d_out, int out_size, void* d_ws, size_t ws_size,
                              hipStream_t stream) {
  char* ws = (char*)d_ws;
  size_t off = 0;
  auto alloc = [&](size_t bytes) -> void* {
    void* p = ws + off;
    off += (bytes + 255) & ~(size_t)255;
    return p;
  };
  const int f32_idx[10] = {3, 4, 6, 7, 8, 9, 11, 12, 13, 14};
  const int b16_idx[3]  = {2, 5, 10};
  float*    f32c[15] = {nullptr};
  uint16_t* b16c[15] = {nullptr};
  for (int j = 0; j < 10; ++j) {
    int i = f32_idx[j];
    f32c[i] = (float*)alloc((size_t)in_sizes[i] * 4);
  }
  for (int j = 0; j < 3; ++j) {
    int i = b16_idx[j];
    b16c[i] = (uint16_t*)alloc((size_t)in_sizes[i] * 2);
  }
  float*    residual = (float*)alloc((size_t)MROWS * DM * 4);
  uint16_t* rmsb16   = (uint16_t*)alloc((size_t)MROWS * DM * 2);
  uint16_t* zh16     = (uint16_t*)alloc((size_t)MROWS * 512 * 2);
  float*    xdbl     = (float*)alloc((size_t)MROWS * 16 * 4);
  float*    hend     = (float*)alloc((size_t)B_ * NCHUNK * DIN * 16 * 4);
  float*    hin      = (float*)alloc((size_t)B_ * NCHUNK * DIN * 16 * 4);
  float*    yloc     = (float*)alloc((size_t)MROWS * DIN * 4);
  float*    Ssum     = (float*)alloc((size_t)MROWS * DIN * 4);
  int*      order    = (int*)alloc((size_t)B_ * LVIS * 4);
  int*      flags    = (int*)alloc(256);

  detect_kernel<<<1, 256, 0, stream>>>(d_in[1], (const uint32_t*)d_in[12], flags);

  CvtArgs ca;
  int total = 0, slot = 0;
  for (int j = 0; j < 3; ++j) {
    int i = b16_idx[j];
    ca.src[slot] = d_in[i]; ca.dst[slot] = b16c[i];
    ca.n[slot] = in_sizes[i]; ca.isb16[slot] = 1;
    total += in_sizes[i]; ++slot;
  }
  for (int j = 0; j < 10; ++j) {
    int i = f32_idx[j];
    ca.src[slot] = d_in[i]; ca.dst[slot] = f32c[i];
    ca.n[slot] = in_sizes[i]; ca.isb16[slot] = 0;
    total += in_sizes[i]; ++slot;
  }
  cvt_all_kernel<<<(total + 255) / 256, 256, 0, stream>>>(ca, total, flags);

  const uint16_t* in_w   = b16c[2];
  const float*    conv_w = f32c[3];
  const float*    conv_b = f32c[4];
  const uint16_t* x_w    = b16c[5];
  const float*    dt_w   = f32c[6];
  const float*    dt_b   = f32c[7];
  const float*    A_log  = f32c[8];
  const float*    D_skip = f32c[9];
  const uint16_t* out_w  = b16c[10];
  const float*    norm_w = f32c[11];
  const float*    norm_f = f32c[12];
  const float*    ln_w   = f32c[13];
  const float*    ln_b   = f32c[14];

  order_kernel<<<B_, 1024, 0, stream>>>(d_in[1], flags, order);
  gather_rms_kernel<<<MROWS, 256, 0, stream>>>(d_in[0], order, flags, norm_w,
                                               residual, rmsb16);

  for (int L = 0; L < DEPTH; ++L) {
    scan1_kernel<<<B_ * NCHUNK, 1024, 0, stream>>>(
        rmsb16, in_w + (size_t)L * 1024 * DM, x_w + (size_t)L * 48 * DIN,
        conv_w + (size_t)L * DIN * 4, conv_b + (size_t)L * DIN,
        dt_w + (size_t)L * DIN * 16, dt_b + (size_t)L * DIN,
        A_log + (size_t)L * DIN * 16, D_skip + (size_t)L * DIN,
        zh16, hend, xdbl, yloc, Ssum);
    scan2_kernel<<<(B_ * 16 * DIN * 4) / 256, 256, 0, stream>>>(
        hend, Ssum, A_log + (size_t)L * DIN * 16, hin);
    int Lnext = (L + 1 < DEPTH) ? (L + 1) : L;
    if (L + 1 < DEPTH) {
      scan3_fused_kernel<0><<<B_ * NCHUNK, 1024, 0, stream>>>(
          zh16, xdbl, A_log + (size_t)L * DIN * 16, hin, yloc, Ssum,
          out_w + (size_t)L * DM * DIN, norm_w + (size_t)Lnext * DM,
          residual, rmsb16, norm_f, ln_w, ln_b, flags, d_out);
    } else {
      scan3_fused_kernel<1><<<B_ * NCHUNK, 1024, 0, stream>>>(
          zh16, xdbl, A_log + (size_t)L * DIN * 16, hin, yloc, Ssum,
          out_w + (size_t)L * DM * DIN, norm_w + (size_t)Lnext * DM,
          residual, rmsb16, norm_f, ln_w, ln_b, flags, d_out);
    }
  }
}